// Round 6
// baseline (259.739 us; speedup 1.0000x reference)
//
#include <hip/hip_runtime.h>
#include <hip/hip_bf16.h>
#include <math.h>

#define D_MODEL 1024
#define SEQ     1024
#define BATCH   4
#define NHEADS  16
#define HD      64

// log2(e) folds: p = exp2(s') with s' = (q.k)*0.125*log2e + 0.05*log2e*(kimp+vimp)
#define QSC 0.18033688f   // 0.125 * log2(e)
#define BSC 0.072134752f  // 0.05  * log2(e)

typedef __bf16 bf16x8 __attribute__((ext_vector_type(8)));
typedef __bf16 bf16x4 __attribute__((ext_vector_type(4)));
typedef float  f32x4  __attribute__((ext_vector_type(4)));

__device__ __forceinline__ f32x4 mfma16(bf16x8 a, bf16x8 b, f32x4 c) {
  return __builtin_amdgcn_mfma_f32_16x16x32_bf16(a, b, c, 0, 0, 0);
}

// async global->LDS, 16B per lane; LDS dest = wave-uniform base + lane*16
__device__ __forceinline__ void async16(__bf16* lds, const __bf16* g) {
  __builtin_amdgcn_global_load_lds(g, lds, 16, 0, 0);
}

// ------------------------------------------ fused prep: cvt x, cvt weights, imp
__global__ __launch_bounds__(256) void prep_kernel(
    const float* __restrict__ x,
    const float* __restrict__ Wq, const float* __restrict__ Wk,
    const float* __restrict__ Wv, const float* __restrict__ Wo,
    const float* __restrict__ k_ema, const float* __restrict__ v_ema,
    const float* __restrict__ Wimp, const float* __restrict__ bimp,
    __bf16* __restrict__ x_bf, __bf16* __restrict__ wq_bf, __bf16* __restrict__ wk_bf,
    __bf16* __restrict__ wv_bf, __bf16* __restrict__ wo_bf,
    float* __restrict__ kimp, float* __restrict__ vimp) {
  const int bid = blockIdx.x;
  const int tid = threadIdx.x;
  if (bid < 4096) {                       // x: 4M floats = 1M float4
    int i = bid * 256 + tid;
    float4 v = ((const float4*)x)[i];
    bf16x4 o; o[0] = (__bf16)v.x; o[1] = (__bf16)v.y; o[2] = (__bf16)v.z; o[3] = (__bf16)v.w;
    ((bf16x4*)x_bf)[i] = o;
  } else if (bid < 8192) {                // 4 weight mats: 4 x 256K float4
    int i = (bid - 4096) * 256 + tid;
    int sel = i >> 18;
    int j = i & 262143;
    const float* s = (sel == 0) ? Wq : (sel == 1) ? Wk : (sel == 2) ? Wv : Wo;
    __bf16* d      = (sel == 0) ? wq_bf : (sel == 1) ? wk_bf : (sel == 2) ? wv_bf : wo_bf;
    float4 v = ((const float4*)s)[j];
    bf16x4 o; o[0] = (__bf16)v.x; o[1] = (__bf16)v.y; o[2] = (__bf16)v.z; o[3] = (__bf16)v.w;
    ((bf16x4*)d)[j] = o;
  } else {                                // imp: one wave per output, 32768 waves
    int gw   = (bid - 8192) * 4 + (tid >> 6);
    int lane = tid & 63;
    int sel  = gw >> 14;
    int rem  = gw & 16383;
    int h = rem >> 10, s = rem & 1023;
    const float* ema = sel ? v_ema : k_ema;
    float sum = 0.f;
    for (int d = lane; d < D_MODEL; d += 64)
      sum += ema[s * D_MODEL + d] * Wimp[h * D_MODEL + d];
    for (int mm = 32; mm >= 1; mm >>= 1) sum += __shfl_xor(sum, mm);
    if (lane == 0) (sel ? vimp : kimp)[h * SEQ + s] = sum + bimp[h];
  }
}

// ---------------------------------------------------- C[M,N] = (A[M,K]·W[N,K]^T + bias)*sc
// m97 structure: 128x128 tile, BK=32, global_load_lds width-16 into swizzled [128][32].
// z==1 (K proj): computes TRANSPOSED product (mfma(b,a)) and writes packed Kp[bh][key][64].
// z==2 (V proj): writes chunk-packed Vp[bh][key>>6][d][key&63].
template<bool OUT_BF16>
__global__ __launch_bounds__(256) void gemm_bt(
    const __bf16* __restrict__ A,
    const __bf16* __restrict__ W0, const __bf16* __restrict__ W1, const __bf16* __restrict__ W2,
    const float* __restrict__ b0, const float* __restrict__ b1, const float* __restrict__ b2,
    void* out0, void* out1, void* out2, float sc0, float sc1, float sc2) {
  const int z = blockIdx.z;
  const __bf16* W   = (z == 0) ? W0 : (z == 1) ? W1 : W2;
  const float* bias = (z == 0) ? b0 : (z == 1) ? b1 : b2;
  void* out         = (z == 0) ? out0 : (z == 1) ? out1 : out2;
  const float sc    = (z == 0) ? sc0 : (z == 1) ? sc1 : sc2;

  __shared__ __bf16 As[128 * 32];
  __shared__ __bf16 Bs[128 * 32];

  const int tid = threadIdx.x;
  const int w = tid >> 6, l = tid & 63;
  const int quad = l >> 4, l16 = l & 15;
  const int wy = w >> 1, wx = w & 1;
  const int row0 = blockIdx.y * 128;
  const int col0 = blockIdx.x * 128;

  const f32x4 fzero = {0.f, 0.f, 0.f, 0.f};
  f32x4 acc[4][4];
  for (int i = 0; i < 4; i++)
    for (int j = 0; j < 4; j++) acc[i][j] = fzero;

  const int lr = l >> 2;                         // 0..15
  const int sw0 = (((l & 3) ^ (lr & 3)) * 8);    // source k offset (swizzled)
  const int rowA = w * 16 + lr;
  const __bf16* aptr = A + (size_t)(row0 + rowA) * D_MODEL + sw0;
  const __bf16* bptr = W + (size_t)(col0 + rowA) * D_MODEL + sw0;
  __bf16* lA0 = &As[w * 512 + l * 8];
  __bf16* lA1 = &As[2048 + w * 512 + l * 8];
  __bf16* lB0 = &Bs[w * 512 + l * 8];
  __bf16* lB1 = &Bs[2048 + w * 512 + l * 8];

  const int rswz = (quad ^ (l16 & 3)) * 8;

  for (int k0 = 0; k0 < D_MODEL; k0 += 32) {
    async16(lA0, aptr + k0);
    async16(lA1, aptr + (size_t)64 * D_MODEL + k0);
    async16(lB0, bptr + k0);
    async16(lB1, bptr + (size_t)64 * D_MODEL + k0);
    __syncthreads();
    bf16x8 af[4], bfr[4];
    #pragma unroll
    for (int mi = 0; mi < 4; mi++) af[mi]  = *(const bf16x8*)&As[(wy * 64 + mi * 16 + l16) * 32 + rswz];
    #pragma unroll
    for (int ni = 0; ni < 4; ni++) bfr[ni] = *(const bf16x8*)&Bs[(wx * 64 + ni * 16 + l16) * 32 + rswz];
    if (z == 1) {
      #pragma unroll
      for (int mi = 0; mi < 4; mi++)
        #pragma unroll
        for (int ni = 0; ni < 4; ni++)
          acc[mi][ni] = mfma16(bfr[ni], af[mi], acc[mi][ni]);   // transposed product
    } else {
      #pragma unroll
      for (int mi = 0; mi < 4; mi++)
        #pragma unroll
        for (int ni = 0; ni < 4; ni++)
          acc[mi][ni] = mfma16(af[mi], bfr[ni], acc[mi][ni]);
    }
    __syncthreads();
  }

  if (z == 1 && OUT_BF16) {
    // D[wcol = quad*4+r within ni-tile][token = l16]: pack 4 hd dims per uint2
    __bf16* kp = (__bf16*)out;
    #pragma unroll
    for (int ni = 0; ni < 4; ni++) {
      const int wcolbase = col0 + wx * 64 + ni * 16 + quad * 4;
      const float4 b4 = *(const float4*)&bias[wcolbase];
      const float bb[4] = {b4.x, b4.y, b4.z, b4.w};
      #pragma unroll
      for (int mi = 0; mi < 4; mi++) {
        const int token = row0 + wy * 64 + mi * 16 + l16;
        const int bh = (token >> 10) * 16 + (wcolbase >> 6);
        union { __bf16 hh[4]; uint2 uu; } pk;
        #pragma unroll
        for (int r = 0; r < 4; r++) pk.hh[r] = (__bf16)(acc[mi][ni][r] + bb[r]);
        *(uint2*)(kp + ((size_t)bh * SEQ + (token & 1023)) * HD + (wcolbase & 63)) = pk.uu;
      }
    }
  } else if (z == 2 && OUT_BF16) {
    // chunk-packed Vp[bh][token>>6][d][token&63], 4 tokens per uint2
    __bf16* vp = (__bf16*)out;
    #pragma unroll
    for (int ni = 0; ni < 4; ni++) {
      const int col = col0 + wx * 64 + ni * 16 + l16;          // d (model dim)
      const float bv = bias[col];
      #pragma unroll
      for (int mi = 0; mi < 4; mi++) {
        const int token = row0 + wy * 64 + mi * 16 + quad * 4;
        const int bh = (token >> 10) * 16 + (col >> 6);
        const int ch = (token >> 6) & 15;
        const size_t base = (((size_t)bh * 16 + ch) * 64 + (col & 63)) * 64 + (token & 63);
        union { __bf16 hh[4]; uint2 uu; } pk;
        #pragma unroll
        for (int r = 0; r < 4; r++) pk.hh[r] = (__bf16)(acc[mi][ni][r] + bv);
        *(uint2*)(vp + base) = pk.uu;
      }
    }
  } else {
    #pragma unroll
    for (int ni = 0; ni < 4; ni++) {
      const int col = col0 + wx * 64 + ni * 16 + l16;
      const float bv = bias[col];
      #pragma unroll
      for (int mi = 0; mi < 4; mi++) {
        const int row = row0 + wy * 64 + mi * 16 + quad * 4;
        #pragma unroll
        for (int r = 0; r < 4; r++) {
          float v = (acc[mi][ni][r] + bv) * sc;
          if (OUT_BF16) ((__bf16*)out)[(size_t)(row + r) * D_MODEL + col] = (__bf16)v;
          else          ((float*)out)[(size_t)(row + r) * D_MODEL + col] = v;
        }
      }
    }
  }
}

// ------------------------------------------------------- attention, independent waves
// K/V chunk-contiguous per head (8 KB blocks): per-chunk working set 16 KB, L1-shared
// across the 8 same-bh blocks per CU. No barriers, no online max (scores bounded).
template<bool DIAG>
__device__ __forceinline__ void attn_chunk(
    const __bf16* __restrict__ kbase, const __bf16* __restrict__ vbase,
    const float* __restrict__ vimpH, int kc, int ch, int qrow,
    int quad, int l16, __bf16 (*Psw)[72],
    bf16x8 qa0, bf16x8 qa1, float sbias,
    float& l_i, f32x4* o) {
  // V^T frags early (used late -> latency hidden by score/softmax work)
  const __bf16* vchunk = vbase + (size_t)ch * (HD * 64);
  bf16x8 vf0[4], vf1[4];
  #pragma unroll
  for (int td = 0; td < 4; td++) {
    const __bf16* vp = vchunk + (td * 16 + l16) * 64;
    vf0[td] = *(const bf16x8*)(vp + quad * 8);
    vf1[td] = *(const bf16x8*)(vp + 32 + quad * 8);
  }
  float p[4][4];
  float lsum = 0.f;
  #pragma unroll
  for (int t = 0; t < 4; t++) {
    const float4 vi = *(const float4*)(vimpH + kc + t * 16 + quad * 4);
    f32x4 sacc;
    sacc[0] = sbias + BSC * vi.x; sacc[1] = sbias + BSC * vi.y;
    sacc[2] = sbias + BSC * vi.z; sacc[3] = sbias + BSC * vi.w;
    const __bf16* kp = kbase + (size_t)(kc + t * 16 + l16) * HD;
    sacc = mfma16(*(const bf16x8*)(kp + quad * 8), qa0, sacc);
    sacc = mfma16(*(const bf16x8*)(kp + 32 + quad * 8), qa1, sacc);
    #pragma unroll
    for (int r = 0; r < 4; r++) {
      float xx = sacc[r];
      if (DIAG) { if (kc + t * 16 + quad * 4 + r > qrow) xx = -3.0e38f; }
      float pp = exp2f(xx);
      p[t][r] = pp;
      lsum += pp;
    }
  }
  l_i += lsum;
  // P: C-layout [key][q] -> per-wave LDS -> B-frag [q][key]
  #pragma unroll
  for (int t = 0; t < 4; t++) {
    union { __bf16 hh[4]; uint2 uu; } pk;
    #pragma unroll
    for (int r = 0; r < 4; r++) pk.hh[r] = (__bf16)p[t][r];
    *(uint2*)&Psw[l16][t * 16 + quad * 4] = pk.uu;
  }
  bf16x8 pf0 = *(const bf16x8*)&Psw[l16][quad * 8];
  bf16x8 pf1 = *(const bf16x8*)&Psw[l16][32 + quad * 8];
  #pragma unroll
  for (int td = 0; td < 4; td++) {
    o[td] = mfma16(vf0[td], pf0, o[td]);
    o[td] = mfma16(vf1[td], pf1, o[td]);
  }
}

__global__ __launch_bounds__(128, 4) void attn_kernel(
    const __bf16* __restrict__ Qb, const __bf16* __restrict__ Kp,
    const __bf16* __restrict__ Vp, const float* __restrict__ kimp,
    const float* __restrict__ vimp, __bf16* __restrict__ Ob) {
  const int id = blockIdx.x;
  const int bh = id & 63;                  // CU c hosts ids c+256k -> same bh: L1/L2 share
  const int g2 = id >> 6;                  // 0..31
  const int b = bh >> 4, h = bh & 15;
  const int wave = threadIdx.x >> 6, lane = threadIdx.x & 63;
  const int quad = lane >> 4, l16 = lane & 15;
  const int qt = wave ? (63 - g2) : g2;    // in-block snake: block work uniform ~17 chunks

  __shared__ __bf16 Ps[2][16][72];

  const __bf16* kbase = Kp + ((size_t)bh * SEQ * HD);   // [key][64] packed
  const __bf16* vbase = Vp + ((size_t)bh * SEQ * HD);   // [ch][64][64] packed
  const float* vimpH = vimp + h * SEQ;

  const int q0 = qt * 16;
  const int qrow = q0 + l16;
  const __bf16* qp = Qb + (size_t)(b * SEQ + qrow) * D_MODEL + h * HD;
  bf16x8 qa0 = *(const bf16x8*)(qp + quad * 8);          // Q pre-scaled by QSC in gemm
  bf16x8 qa1 = *(const bf16x8*)(qp + 32 + quad * 8);
  const float sbias = BSC * kimp[h * SEQ + qrow];
  float l_i = 0.f;
  f32x4 o[4];
  #pragma unroll
  for (int td = 0; td < 4; td++) { o[td][0] = 0.f; o[td][1] = 0.f; o[td][2] = 0.f; o[td][3] = 0.f; }

  const int nch = (qt >> 2) + 1;
  for (int ch = 0; ch < nch - 1; ch++)
    attn_chunk<false>(kbase, vbase, vimpH, ch * 64, ch, qrow, quad, l16, Ps[wave],
                      qa0, qa1, sbias, l_i, o);
  attn_chunk<true>(kbase, vbase, vimpH, (nch - 1) * 64, nch - 1, qrow, quad, l16, Ps[wave],
                   qa0, qa1, sbias, l_i, o);

  float L = l_i;
  L += __shfl_xor(L, 16);
  L += __shfl_xor(L, 32);
  const float il = 1.0f / L;
  __bf16* op = Ob + (size_t)(b * SEQ + qrow) * D_MODEL + h * HD;
  #pragma unroll
  for (int td = 0; td < 4; td++) {
    union { __bf16 hh[4]; uint2 uu; } pk;
    #pragma unroll
    for (int r = 0; r < 4; r++) pk.hh[r] = (__bf16)(o[td][r] * il);
    *(uint2*)(op + td * 16 + quad * 4) = pk.uu;
  }
}

// ---------------------------------------------------------------------------
extern "C" void kernel_launch(void* const* d_in, const int* in_sizes, int n_in,
                              void* d_out, int out_size, void* d_ws, size_t ws_size,
                              hipStream_t stream) {
  const float* x     = (const float*)d_in[0];
  const float* Wq    = (const float*)d_in[1];
  const float* bq    = (const float*)d_in[2];
  const float* Wk    = (const float*)d_in[3];
  const float* bk    = (const float*)d_in[4];
  const float* Wv    = (const float*)d_in[5];
  const float* bv    = (const float*)d_in[6];
  const float* Wo    = (const float*)d_in[7];
  const float* bo    = (const float*)d_in[8];
  const float* Wimp  = (const float*)d_in[9];
  const float* bimp  = (const float*)d_in[10];
  const float* k_ema = (const float*)d_in[11];
  const float* v_ema = (const float*)d_in[12];
  float* out = (float*)d_out;

  char* ws = (char*)d_ws;
  __bf16* x_bf  = (__bf16*)(ws);                        // 8 MB
  __bf16* wq_bf = (__bf16*)(ws + (8ull  << 20));        // 2 MB each
  __bf16* wk_bf = (__bf16*)(ws + (10ull << 20));
  __bf16* wv_bf = (__bf16*)(ws + (12ull << 20));
  __bf16* wo_bf = (__bf16*)(ws + (14ull << 20));
  __bf16* q_bf  = (__bf16*)(ws + (16ull << 20));        // 8 MB each
  __bf16* kp_bf = (__bf16*)(ws + (24ull << 20));        // K packed [bh][key][64]
  __bf16* vp_bf = (__bf16*)(ws + (32ull << 20));        // V packed [bh][ch][d][64]
  __bf16* a_bf  = (__bf16*)(ws + (40ull << 20));
  float*  kimp  = (float*)(ws + (48ull << 20));         // 64 KB
  float*  vimp  = (float*)(ws + (48ull << 20) + (64ull << 10));

  prep_kernel<<<16384, 256, 0, stream>>>(
      x, Wq, Wk, Wv, Wo, k_ema, v_ema, Wimp, bimp,
      x_bf, wq_bf, wk_bf, wv_bf, wo_bf, kimp, vimp);

  // Q,K,V projections; Q pre-scaled by 0.125*log2(e); K,V written per-head packed
  gemm_bt<true><<<dim3(8, 32, 3), 256, 0, stream>>>(
      x_bf, wq_bf, wk_bf, wv_bf, bq, bk, bv,
      (void*)q_bf, (void*)kp_bf, (void*)vp_bf, QSC, 1.0f, 1.0f);

  attn_kernel<<<dim3(2048), 128, 0, stream>>>(
      q_bf, kp_bf, vp_bf, kimp, vimp, a_bf);

  gemm_bt<false><<<dim3(8, 32, 1), 256, 0, stream>>>(
      a_bf, wo_bf, wo_bf, wo_bf, bo, bo, bo,
      (void*)out, (void*)out, (void*)out, 1.0f, 1.0f, 1.0f);
}

// Round 7
// 251.593 us; speedup vs baseline: 1.0324x; 1.0324x over previous
//
#include <hip/hip_runtime.h>
#include <hip/hip_bf16.h>
#include <math.h>

#define D_MODEL 1024
#define SEQ     1024
#define BATCH   4
#define NHEADS  16
#define HD      64

// log2(e) folds: p = exp2(s') with s' = (q.k)*0.125*log2e + 0.05*log2e*vimp
// (kimp term is constant per q-row -> cancels in softmax; dropped entirely)
#define QSC 0.18033688f   // 0.125 * log2(e)
#define BSC 0.072134752f  // 0.05  * log2(e)

typedef __bf16 bf16x8 __attribute__((ext_vector_type(8)));
typedef __bf16 bf16x4 __attribute__((ext_vector_type(4)));
typedef float  f32x4  __attribute__((ext_vector_type(4)));

__device__ __forceinline__ f32x4 mfma16(bf16x8 a, bf16x8 b, f32x4 c) {
  return __builtin_amdgcn_mfma_f32_16x16x32_bf16(a, b, c, 0, 0, 0);
}

// async global->LDS, 16B per lane; LDS dest = wave-uniform base + lane*16
__device__ __forceinline__ void async16(__bf16* lds, const __bf16* g) {
  __builtin_amdgcn_global_load_lds(g, lds, 16, 0, 0);
}

// ------------------------------------------ fused prep: cvt x, cvt weights, vimp
__global__ __launch_bounds__(256) void prep_kernel(
    const float* __restrict__ x,
    const float* __restrict__ Wq, const float* __restrict__ Wk,
    const float* __restrict__ Wv, const float* __restrict__ Wo,
    const float* __restrict__ v_ema,
    const float* __restrict__ Wimp, const float* __restrict__ bimp,
    __bf16* __restrict__ x_bf, __bf16* __restrict__ wq_bf, __bf16* __restrict__ wk_bf,
    __bf16* __restrict__ wv_bf, __bf16* __restrict__ wo_bf,
    float* __restrict__ vimp) {
  const int bid = blockIdx.x;
  const int tid = threadIdx.x;
  if (bid < 4096) {                       // x: 4M floats = 1M float4
    int i = bid * 256 + tid;
    float4 v = ((const float4*)x)[i];
    bf16x4 o; o[0] = (__bf16)v.x; o[1] = (__bf16)v.y; o[2] = (__bf16)v.z; o[3] = (__bf16)v.w;
    ((bf16x4*)x_bf)[i] = o;
  } else if (bid < 8192) {                // 4 weight mats: 4 x 256K float4
    int i = (bid - 4096) * 256 + tid;
    int sel = i >> 18;
    int j = i & 262143;
    const float* s = (sel == 0) ? Wq : (sel == 1) ? Wk : (sel == 2) ? Wv : Wo;
    __bf16* d      = (sel == 0) ? wq_bf : (sel == 1) ? wk_bf : (sel == 2) ? wv_bf : wo_bf;
    float4 v = ((const float4*)s)[j];
    bf16x4 o; o[0] = (__bf16)v.x; o[1] = (__bf16)v.y; o[2] = (__bf16)v.z; o[3] = (__bf16)v.w;
    ((bf16x4*)d)[j] = o;
  } else {                                // vimp: one wave per (h,s), 16384 waves
    int gw   = (bid - 8192) * 4 + (tid >> 6);
    int lane = tid & 63;
    int h = gw >> 10, s = gw & 1023;
    float sum = 0.f;
    for (int d = lane; d < D_MODEL; d += 64)
      sum += v_ema[s * D_MODEL + d] * Wimp[h * D_MODEL + d];
    for (int mm = 32; mm >= 1; mm >>= 1) sum += __shfl_xor(sum, mm);
    if (lane == 0) vimp[h * SEQ + s] = sum + bimp[h];
  }
}

// ---------------------------------------------------- C[M,N] = (A[M,K]·W[N,K]^T + bias)*sc
// m97 structure: 128x128 tile, BK=32, global_load_lds width-16 into swizzled [128][32].
// z==1 (K proj): computes TRANSPOSED product (mfma(b,a)) and writes packed Kp[bh][key][64].
// z==2 (V proj): writes chunk-packed Vp[bh][key>>6][d][key&63].
template<bool OUT_BF16>
__global__ __launch_bounds__(256) void gemm_bt(
    const __bf16* __restrict__ A,
    const __bf16* __restrict__ W0, const __bf16* __restrict__ W1, const __bf16* __restrict__ W2,
    const float* __restrict__ b0, const float* __restrict__ b1, const float* __restrict__ b2,
    void* out0, void* out1, void* out2, float sc0, float sc1, float sc2) {
  const int z = blockIdx.z;
  const __bf16* W   = (z == 0) ? W0 : (z == 1) ? W1 : W2;
  const float* bias = (z == 0) ? b0 : (z == 1) ? b1 : b2;
  void* out         = (z == 0) ? out0 : (z == 1) ? out1 : out2;
  const float sc    = (z == 0) ? sc0 : (z == 1) ? sc1 : sc2;

  __shared__ __bf16 As[128 * 32];
  __shared__ __bf16 Bs[128 * 32];

  const int tid = threadIdx.x;
  const int w = tid >> 6, l = tid & 63;
  const int quad = l >> 4, l16 = l & 15;
  const int wy = w >> 1, wx = w & 1;
  const int row0 = blockIdx.y * 128;
  const int col0 = blockIdx.x * 128;

  const f32x4 fzero = {0.f, 0.f, 0.f, 0.f};
  f32x4 acc[4][4];
  for (int i = 0; i < 4; i++)
    for (int j = 0; j < 4; j++) acc[i][j] = fzero;

  const int lr = l >> 2;                         // 0..15
  const int sw0 = (((l & 3) ^ (lr & 3)) * 8);    // source k offset (swizzled)
  const int rowA = w * 16 + lr;
  const __bf16* aptr = A + (size_t)(row0 + rowA) * D_MODEL + sw0;
  const __bf16* bptr = W + (size_t)(col0 + rowA) * D_MODEL + sw0;
  __bf16* lA0 = &As[w * 512 + l * 8];
  __bf16* lA1 = &As[2048 + w * 512 + l * 8];
  __bf16* lB0 = &Bs[w * 512 + l * 8];
  __bf16* lB1 = &Bs[2048 + w * 512 + l * 8];

  const int rswz = (quad ^ (l16 & 3)) * 8;

  for (int k0 = 0; k0 < D_MODEL; k0 += 32) {
    async16(lA0, aptr + k0);
    async16(lA1, aptr + (size_t)64 * D_MODEL + k0);
    async16(lB0, bptr + k0);
    async16(lB1, bptr + (size_t)64 * D_MODEL + k0);
    __syncthreads();
    bf16x8 af[4], bfr[4];
    #pragma unroll
    for (int mi = 0; mi < 4; mi++) af[mi]  = *(const bf16x8*)&As[(wy * 64 + mi * 16 + l16) * 32 + rswz];
    #pragma unroll
    for (int ni = 0; ni < 4; ni++) bfr[ni] = *(const bf16x8*)&Bs[(wx * 64 + ni * 16 + l16) * 32 + rswz];
    if (z == 1) {
      #pragma unroll
      for (int mi = 0; mi < 4; mi++)
        #pragma unroll
        for (int ni = 0; ni < 4; ni++)
          acc[mi][ni] = mfma16(bfr[ni], af[mi], acc[mi][ni]);   // transposed product
    } else {
      #pragma unroll
      for (int mi = 0; mi < 4; mi++)
        #pragma unroll
        for (int ni = 0; ni < 4; ni++)
          acc[mi][ni] = mfma16(af[mi], bfr[ni], acc[mi][ni]);
    }
    __syncthreads();
  }

  if (z == 1 && OUT_BF16) {
    // D[wcol = quad*4+r within ni-tile][token = l16]: pack 4 hd dims per uint2
    __bf16* kp = (__bf16*)out;
    #pragma unroll
    for (int ni = 0; ni < 4; ni++) {
      const int wcolbase = col0 + wx * 64 + ni * 16 + quad * 4;
      const float4 b4 = *(const float4*)&bias[wcolbase];
      const float bb[4] = {b4.x, b4.y, b4.z, b4.w};
      #pragma unroll
      for (int mi = 0; mi < 4; mi++) {
        const int token = row0 + wy * 64 + mi * 16 + l16;
        const int bh = (token >> 10) * 16 + (wcolbase >> 6);
        union { __bf16 hh[4]; uint2 uu; } pk;
        #pragma unroll
        for (int r = 0; r < 4; r++) pk.hh[r] = (__bf16)(acc[mi][ni][r] + bb[r]);
        *(uint2*)(kp + ((size_t)bh * SEQ + (token & 1023)) * HD + (wcolbase & 63)) = pk.uu;
      }
    }
  } else if (z == 2 && OUT_BF16) {
    // chunk-packed Vp[bh][token>>6][d][token&63], 4 tokens per uint2
    __bf16* vp = (__bf16*)out;
    #pragma unroll
    for (int ni = 0; ni < 4; ni++) {
      const int col = col0 + wx * 64 + ni * 16 + l16;          // d (model dim)
      const float bv = bias[col];
      #pragma unroll
      for (int mi = 0; mi < 4; mi++) {
        const int token = row0 + wy * 64 + mi * 16 + quad * 4;
        const int bh = (token >> 10) * 16 + (col >> 6);
        const int ch = (token >> 6) & 15;
        const size_t base = (((size_t)bh * 16 + ch) * 64 + (col & 63)) * 64 + (token & 63);
        union { __bf16 hh[4]; uint2 uu; } pk;
        #pragma unroll
        for (int r = 0; r < 4; r++) pk.hh[r] = (__bf16)(acc[mi][ni][r] + bv);
        *(uint2*)(vp + base) = pk.uu;
      }
    }
  } else {
    #pragma unroll
    for (int ni = 0; ni < 4; ni++) {
      const int col = col0 + wx * 64 + ni * 16 + l16;
      const float bv = bias[col];
      #pragma unroll
      for (int mi = 0; mi < 4; mi++) {
        const int row = row0 + wy * 64 + mi * 16 + quad * 4;
        #pragma unroll
        for (int r = 0; r < 4; r++) {
          float v = (acc[mi][ni][r] + bv) * sc;
          if (OUT_BF16) ((__bf16*)out)[(size_t)(row + r) * D_MODEL + col] = (__bf16)v;
          else          ((float*)out)[(size_t)(row + r) * D_MODEL + col] = v;
        }
      }
    }
  }
}

// ------------------------------------------------------- attention, reg-prefetched
// Per-chunk latency was the wall (~10.6k cyc: serialized loads). Fix: K frags
// double-buffered in registers across chunks (ping-pong, no copies); V/vimp issued
// at compute start, used ~300cyc later. launch_bounds(128,2) -> 256 VGPR budget.
struct KFrags { bf16x8 kf[8]; };

__device__ __forceinline__ void load_k(KFrags& R, const __bf16* __restrict__ kbase,
                                       int kc, int quad, int l16) {
  #pragma unroll
  for (int t = 0; t < 4; t++) {
    const __bf16* kp = kbase + (size_t)(kc + t * 16 + l16) * HD;
    R.kf[2 * t]     = *(const bf16x8*)(kp + quad * 8);
    R.kf[2 * t + 1] = *(const bf16x8*)(kp + 32 + quad * 8);
  }
}

__device__ __forceinline__ void compute_chunk(
    const KFrags& R, const __bf16* __restrict__ vbase, const float* __restrict__ vimpH,
    int kc, int klim, int quad, int l16, __bf16 (*Psw)[72],
    bf16x8 qa0, bf16x8 qa1, float& l_i, f32x4* o) {
  // V frags for this chunk: used late -> issue first
  const __bf16* vchunk = vbase + (size_t)kc * HD;    // chunk base = ch*64*64
  bf16x8 vf[8];
  #pragma unroll
  for (int td = 0; td < 4; td++) {
    const __bf16* vp = vchunk + (td * 16 + l16) * 64;
    vf[2 * td]     = *(const bf16x8*)(vp + quad * 8);
    vf[2 * td + 1] = *(const bf16x8*)(vp + 32 + quad * 8);
  }
  float4 vi[4];
  #pragma unroll
  for (int t = 0; t < 4; t++) vi[t] = *(const float4*)(vimpH + kc + t * 16 + quad * 4);

  const f32x4 fz = {0.f, 0.f, 0.f, 0.f};
  float p[4][4];
  float lsum = 0.f;
  #pragma unroll
  for (int t = 0; t < 4; t++) {
    f32x4 sacc = fz;                                  // bias added post-MFMA (keeps MFMA
    sacc = mfma16(R.kf[2 * t], qa0, sacc);            //  independent of the vi load)
    sacc = mfma16(R.kf[2 * t + 1], qa1, sacc);
    const float vib[4] = {vi[t].x, vi[t].y, vi[t].z, vi[t].w};
    #pragma unroll
    for (int r = 0; r < 4; r++) {
      float pp = exp2f(sacc[r] + BSC * vib[r]);
      pp = (kc + t * 16 + quad * 4 + r <= klim) ? pp : 0.f;   // causal
      p[t][r] = pp;
      lsum += pp;
    }
  }
  l_i += lsum;
  // P: C-layout [key][q] -> per-wave LDS -> B-frag [q][key]
  #pragma unroll
  for (int t = 0; t < 4; t++) {
    union { __bf16 hh[4]; uint2 uu; } pk;
    #pragma unroll
    for (int r = 0; r < 4; r++) pk.hh[r] = (__bf16)p[t][r];
    *(uint2*)&Psw[l16][t * 16 + quad * 4] = pk.uu;
  }
  bf16x8 pf0 = *(const bf16x8*)&Psw[l16][quad * 8];
  bf16x8 pf1 = *(const bf16x8*)&Psw[l16][32 + quad * 8];
  #pragma unroll
  for (int td = 0; td < 4; td++) {
    o[td] = mfma16(vf[2 * td], pf0, o[td]);
    o[td] = mfma16(vf[2 * td + 1], pf1, o[td]);
  }
}

__global__ __launch_bounds__(128, 2) void attn_kernel(
    const __bf16* __restrict__ Qb, const __bf16* __restrict__ Kp,
    const __bf16* __restrict__ Vp, const float* __restrict__ vimp,
    __bf16* __restrict__ Ob) {
  const int id = blockIdx.x;
  const int bh = id & 63;                  // CU c hosts ids c+256k -> same bh: L1/L2 share
  const int b = bh >> 4, h = bh & 15;
  const int wave = threadIdx.x >> 6, lane = threadIdx.x & 63;
  const int quad = lane >> 4, l16 = lane & 15;
  const int g = ((id >> 6) << 1) + wave;   // 0..31; wave tiles {g, 63-g}: 16-17 chunks

  __shared__ __bf16 Ps[2][16][72];

  const __bf16* kbase = Kp + ((size_t)bh * SEQ * HD);   // [key][64] packed
  const __bf16* vbase = Vp + ((size_t)bh * SEQ * HD);   // [ch][64][64] packed
  const float* vimpH = vimp + h * SEQ;

  #pragma unroll 1
  for (int ti = 0; ti < 2; ti++) {
    const int qt = ti ? (63 - g) : g;
    const int qrow = qt * 16 + l16;
    const int nch = (qt >> 2) + 1;
    const __bf16* qp = Qb + (size_t)(b * SEQ + qrow) * D_MODEL + h * HD;
    bf16x8 qa0 = *(const bf16x8*)(qp + quad * 8);        // Q pre-scaled by QSC in gemm
    bf16x8 qa1 = *(const bf16x8*)(qp + 32 + quad * 8);
    float l_i = 0.f;
    f32x4 o[4];
    #pragma unroll
    for (int td = 0; td < 4; td++) { o[td][0] = 0.f; o[td][1] = 0.f; o[td][2] = 0.f; o[td][3] = 0.f; }

    KFrags RA, RB;
    load_k(RA, kbase, 0, quad, l16);
    int ch = 0;
    while (true) {
      bool last = (ch == nch - 1);
      if (!last) load_k(RB, kbase, (ch + 1) * 64, quad, l16);
      compute_chunk(RA, vbase, vimpH, ch * 64, last ? qrow : (SEQ - 1),
                    quad, l16, Ps[wave], qa0, qa1, l_i, o);
      if (last) break;
      ch++;
      last = (ch == nch - 1);
      if (!last) load_k(RA, kbase, (ch + 1) * 64, quad, l16);
      compute_chunk(RB, vbase, vimpH, ch * 64, last ? qrow : (SEQ - 1),
                    quad, l16, Ps[wave], qa0, qa1, l_i, o);
      if (last) break;
      ch++;
    }

    float L = l_i;
    L += __shfl_xor(L, 16);
    L += __shfl_xor(L, 32);
    const float il = 1.0f / L;
    __bf16* op = Ob + (size_t)(b * SEQ + qrow) * D_MODEL + h * HD;
    #pragma unroll
    for (int td = 0; td < 4; td++) {
      union { __bf16 hh[4]; uint2 uu; } pk;
      #pragma unroll
      for (int r = 0; r < 4; r++) pk.hh[r] = (__bf16)(o[td][r] * il);
      *(uint2*)(op + td * 16 + quad * 4) = pk.uu;
    }
  }
}

// ---------------------------------------------------------------------------
extern "C" void kernel_launch(void* const* d_in, const int* in_sizes, int n_in,
                              void* d_out, int out_size, void* d_ws, size_t ws_size,
                              hipStream_t stream) {
  const float* x     = (const float*)d_in[0];
  const float* Wq    = (const float*)d_in[1];
  const float* bq    = (const float*)d_in[2];
  const float* Wk    = (const float*)d_in[3];
  const float* bk    = (const float*)d_in[4];
  const float* Wv    = (const float*)d_in[5];
  const float* bv    = (const float*)d_in[6];
  const float* Wo    = (const float*)d_in[7];
  const float* bo    = (const float*)d_in[8];
  const float* Wimp  = (const float*)d_in[9];
  const float* bimp  = (const float*)d_in[10];
  // d_in[11] = k_ema (unused: kimp bias is per-q-row constant, cancels in softmax)
  const float* v_ema = (const float*)d_in[12];
  float* out = (float*)d_out;

  char* ws = (char*)d_ws;
  __bf16* x_bf  = (__bf16*)(ws);                        // 8 MB
  __bf16* wq_bf = (__bf16*)(ws + (8ull  << 20));        // 2 MB each
  __bf16* wk_bf = (__bf16*)(ws + (10ull << 20));
  __bf16* wv_bf = (__bf16*)(ws + (12ull << 20));
  __bf16* wo_bf = (__bf16*)(ws + (14ull << 20));
  __bf16* q_bf  = (__bf16*)(ws + (16ull << 20));        // 8 MB each
  __bf16* kp_bf = (__bf16*)(ws + (24ull << 20));        // K packed [bh][key][64]
  __bf16* vp_bf = (__bf16*)(ws + (32ull << 20));        // V packed [bh][ch][d][64]
  __bf16* a_bf  = (__bf16*)(ws + (40ull << 20));
  float*  vimp  = (float*)(ws + (48ull << 20));         // 64 KB

  prep_kernel<<<12288, 256, 0, stream>>>(
      x, Wq, Wk, Wv, Wo, v_ema, Wimp, bimp,
      x_bf, wq_bf, wk_bf, wv_bf, wo_bf, vimp);

  // Q,K,V projections; Q pre-scaled by 0.125*log2(e); K,V written per-head packed
  gemm_bt<true><<<dim3(8, 32, 3), 256, 0, stream>>>(
      x_bf, wq_bf, wk_bf, wv_bf, bq, bk, bv,
      (void*)q_bf, (void*)kp_bf, (void*)vp_bf, QSC, 1.0f, 1.0f);

  attn_kernel<<<dim3(1024), 128, 0, stream>>>(
      q_bf, kp_bf, vp_bf, vimp, a_bf);

  gemm_bt<false><<<dim3(8, 32, 1), 256, 0, stream>>>(
      a_bf, wo_bf, wo_bf, wo_bf, bo, bo, bo,
      (void*)out, (void*)out, (void*)out, 1.0f, 1.0f, 1.0f);
}

// Round 8
// 215.979 us; speedup vs baseline: 1.2026x; 1.1649x over previous
//
#include <hip/hip_runtime.h>
#include <hip/hip_bf16.h>
#include <math.h>

#define D_MODEL 1024
#define SEQ     1024
#define BATCH   4
#define NHEADS  16
#define HD      64

// log2(e) folds: p = exp2(s') with s' = (q.k)*0.125*log2e + 0.05*log2e*vimp
// (kimp term is constant per q-row -> cancels in softmax; dropped entirely)
#define QSC 0.18033688f   // 0.125 * log2(e)
#define BSC 0.072134752f  // 0.05  * log2(e)

typedef __bf16 bf16x8 __attribute__((ext_vector_type(8)));
typedef __bf16 bf16x4 __attribute__((ext_vector_type(4)));
typedef float  f32x4  __attribute__((ext_vector_type(4)));

__device__ __forceinline__ f32x4 mfma16(bf16x8 a, bf16x8 b, f32x4 c) {
  return __builtin_amdgcn_mfma_f32_16x16x32_bf16(a, b, c, 0, 0, 0);
}

// async global->LDS, 16B per lane; LDS dest = wave-uniform base + lane*16
__device__ __forceinline__ void async16(__bf16* lds, const __bf16* g) {
  __builtin_amdgcn_global_load_lds(g, lds, 16, 0, 0);
}

// ------------------------------------------ fused prep: cvt x, cvt weights, vimp
__global__ __launch_bounds__(256) void prep_kernel(
    const float* __restrict__ x,
    const float* __restrict__ Wq, const float* __restrict__ Wk,
    const float* __restrict__ Wv, const float* __restrict__ Wo,
    const float* __restrict__ v_ema,
    const float* __restrict__ Wimp, const float* __restrict__ bimp,
    __bf16* __restrict__ x_bf, __bf16* __restrict__ wq_bf, __bf16* __restrict__ wk_bf,
    __bf16* __restrict__ wv_bf, __bf16* __restrict__ wo_bf,
    float* __restrict__ vimp) {
  const int bid = blockIdx.x;
  const int tid = threadIdx.x;
  if (bid < 4096) {                       // x: 4M floats = 1M float4
    int i = bid * 256 + tid;
    float4 v = ((const float4*)x)[i];
    bf16x4 o; o[0] = (__bf16)v.x; o[1] = (__bf16)v.y; o[2] = (__bf16)v.z; o[3] = (__bf16)v.w;
    ((bf16x4*)x_bf)[i] = o;
  } else if (bid < 8192) {                // 4 weight mats: 4 x 256K float4
    int i = (bid - 4096) * 256 + tid;
    int sel = i >> 18;
    int j = i & 262143;
    const float* s = (sel == 0) ? Wq : (sel == 1) ? Wk : (sel == 2) ? Wv : Wo;
    __bf16* d      = (sel == 0) ? wq_bf : (sel == 1) ? wk_bf : (sel == 2) ? wv_bf : wo_bf;
    float4 v = ((const float4*)s)[j];
    bf16x4 o; o[0] = (__bf16)v.x; o[1] = (__bf16)v.y; o[2] = (__bf16)v.z; o[3] = (__bf16)v.w;
    ((bf16x4*)d)[j] = o;
  } else {                                // vimp: one wave per (h,s), 16384 waves
    int gw   = (bid - 8192) * 4 + (tid >> 6);
    int lane = tid & 63;
    int h = gw >> 10, s = gw & 1023;
    float sum = 0.f;
    for (int d = lane; d < D_MODEL; d += 64)
      sum += v_ema[s * D_MODEL + d] * Wimp[h * D_MODEL + d];
    for (int mm = 32; mm >= 1; mm >>= 1) sum += __shfl_xor(sum, mm);
    if (lane == 0) vimp[h * SEQ + s] = sum + bimp[h];
  }
}

// ---------------------------------------------------- C[M,N] = (A[M,K]·W[N,K]^T + bias)*sc
// m97 structure: 128x128 tile, BK=32, global_load_lds width-16 into swizzled [128][32].
// z==1 (K proj): TRANSPOSED product, writes Kp[bh][key][64] with row-rotation
//                col' = (col + (key&7)*8) & 63 (bank-uniform b128 LDS reads in attn).
// z==2 (V proj): writes Vp[bh][key>>6][d][64] with key' = (key + (d&7)*8) & 63.
template<bool OUT_BF16>
__global__ __launch_bounds__(256) void gemm_bt(
    const __bf16* __restrict__ A,
    const __bf16* __restrict__ W0, const __bf16* __restrict__ W1, const __bf16* __restrict__ W2,
    const float* __restrict__ b0, const float* __restrict__ b1, const float* __restrict__ b2,
    void* out0, void* out1, void* out2, float sc0, float sc1, float sc2) {
  const int z = blockIdx.z;
  const __bf16* W   = (z == 0) ? W0 : (z == 1) ? W1 : W2;
  const float* bias = (z == 0) ? b0 : (z == 1) ? b1 : b2;
  void* out         = (z == 0) ? out0 : (z == 1) ? out1 : out2;
  const float sc    = (z == 0) ? sc0 : (z == 1) ? sc1 : sc2;

  __shared__ __bf16 As[128 * 32];
  __shared__ __bf16 Bs[128 * 32];

  const int tid = threadIdx.x;
  const int w = tid >> 6, l = tid & 63;
  const int quad = l >> 4, l16 = l & 15;
  const int wy = w >> 1, wx = w & 1;
  const int row0 = blockIdx.y * 128;
  const int col0 = blockIdx.x * 128;

  const f32x4 fzero = {0.f, 0.f, 0.f, 0.f};
  f32x4 acc[4][4];
  for (int i = 0; i < 4; i++)
    for (int j = 0; j < 4; j++) acc[i][j] = fzero;

  const int lr = l >> 2;                         // 0..15
  const int sw0 = (((l & 3) ^ (lr & 3)) * 8);    // source k offset (swizzled)
  const int rowA = w * 16 + lr;
  const __bf16* aptr = A + (size_t)(row0 + rowA) * D_MODEL + sw0;
  const __bf16* bptr = W + (size_t)(col0 + rowA) * D_MODEL + sw0;
  __bf16* lA0 = &As[w * 512 + l * 8];
  __bf16* lA1 = &As[2048 + w * 512 + l * 8];
  __bf16* lB0 = &Bs[w * 512 + l * 8];
  __bf16* lB1 = &Bs[2048 + w * 512 + l * 8];

  const int rswz = (quad ^ (l16 & 3)) * 8;

  for (int k0 = 0; k0 < D_MODEL; k0 += 32) {
    async16(lA0, aptr + k0);
    async16(lA1, aptr + (size_t)64 * D_MODEL + k0);
    async16(lB0, bptr + k0);
    async16(lB1, bptr + (size_t)64 * D_MODEL + k0);
    __syncthreads();
    bf16x8 af[4], bfr[4];
    #pragma unroll
    for (int mi = 0; mi < 4; mi++) af[mi]  = *(const bf16x8*)&As[(wy * 64 + mi * 16 + l16) * 32 + rswz];
    #pragma unroll
    for (int ni = 0; ni < 4; ni++) bfr[ni] = *(const bf16x8*)&Bs[(wx * 64 + ni * 16 + l16) * 32 + rswz];
    if (z == 1) {
      #pragma unroll
      for (int mi = 0; mi < 4; mi++)
        #pragma unroll
        for (int ni = 0; ni < 4; ni++)
          acc[mi][ni] = mfma16(bfr[ni], af[mi], acc[mi][ni]);   // transposed product
    } else {
      #pragma unroll
      for (int mi = 0; mi < 4; mi++)
        #pragma unroll
        for (int ni = 0; ni < 4; ni++)
          acc[mi][ni] = mfma16(af[mi], bfr[ni], acc[mi][ni]);
    }
    __syncthreads();
  }

  if (z == 1 && OUT_BF16) {
    // D[wcol][token]: pack 4 hd dims per uint2, rotated within the 64-dim row
    __bf16* kp = (__bf16*)out;
    #pragma unroll
    for (int ni = 0; ni < 4; ni++) {
      const int wcolbase = col0 + wx * 64 + ni * 16 + quad * 4;
      const float4 b4 = *(const float4*)&bias[wcolbase];
      const float bb[4] = {b4.x, b4.y, b4.z, b4.w};
      #pragma unroll
      for (int mi = 0; mi < 4; mi++) {
        const int token = row0 + wy * 64 + mi * 16 + l16;
        const int bh = (token >> 10) * 16 + (wcolbase >> 6);
        const int colp = ((wcolbase & 63) + ((token & 7) << 3)) & 63;   // rotation
        union { __bf16 hh[4]; uint2 uu; } pk;
        #pragma unroll
        for (int r = 0; r < 4; r++) pk.hh[r] = (__bf16)(acc[mi][ni][r] + bb[r]);
        *(uint2*)(kp + ((size_t)bh * SEQ + (token & 1023)) * HD + colp) = pk.uu;
      }
    }
  } else if (z == 2 && OUT_BF16) {
    // chunk-packed Vp[bh][token>>6][d][token'], rotated in key dim
    __bf16* vp = (__bf16*)out;
    #pragma unroll
    for (int ni = 0; ni < 4; ni++) {
      const int col = col0 + wx * 64 + ni * 16 + l16;          // d (model dim)
      const float bv = bias[col];
      #pragma unroll
      for (int mi = 0; mi < 4; mi++) {
        const int token = row0 + wy * 64 + mi * 16 + quad * 4;
        const int bh = (token >> 10) * 16 + (col >> 6);
        const int chk = (token >> 6) & 15;
        const int keyp = ((token & 63) + ((col & 7) << 3)) & 63;        // rotation
        const size_t base = (((size_t)bh * 16 + chk) * 64 + (col & 63)) * 64 + keyp;
        union { __bf16 hh[4]; uint2 uu; } pk;
        #pragma unroll
        for (int r = 0; r < 4; r++) pk.hh[r] = (__bf16)(acc[mi][ni][r] + bv);
        *(uint2*)(vp + base) = pk.uu;
      }
    }
  } else {
    #pragma unroll
    for (int ni = 0; ni < 4; ni++) {
      const int col = col0 + wx * 64 + ni * 16 + l16;
      const float bv = bias[col];
      #pragma unroll
      for (int mi = 0; mi < 4; mi++) {
        const int row = row0 + wy * 64 + mi * 16 + quad * 4;
        #pragma unroll
        for (int r = 0; r < 4; r++) {
          float v = (acc[mi][ni][r] + bv) * sc;
          if (OUT_BF16) ((__bf16*)out)[(size_t)(row + r) * D_MODEL + col] = (__bf16)v;
          else          ((float*)out)[(size_t)(row + r) * D_MODEL + col] = v;
        }
      }
    }
  }
}

// ------------------------------------------------------- attention, DMA-staged (m97-style)
// Block = 4 waves = 64 q-rows of one (bh, group). K+V chunk (16 KB) DMA'd into
// double-buffered LDS via global_load_lds; ONE barrier per chunk (drains the DMA
// issued during the previous chunk's compute -> ~free). All frag reads are
// ds_read_b128, bank-uniform thanks to the global-side row rotation.
// Snake pairing {g, 15-g}: every block runs exactly 17 chunks.
__global__ __launch_bounds__(256, 2) void attn_kernel(
    const __bf16* __restrict__ Qb, const __bf16* __restrict__ Kp,
    const __bf16* __restrict__ Vp, const float* __restrict__ vimp,
    __bf16* __restrict__ Ob) {
  const int id = blockIdx.x;
  const int bh = id & 63;                 // CU c hosts ids c, c+256 -> same bh: L2 share
  const int gg = id >> 6;                 // 0..7
  const int b = bh >> 4, h = bh & 15;
  const int tid = threadIdx.x;
  const int wave = tid >> 6, lane = tid & 63;
  const int quad = lane >> 4, l16 = lane & 15;

  __shared__ __bf16 Kl[2][4096];          // 64 keys x 64 dims (rotated rows)
  __shared__ __bf16 Vl[2][4096];          // 64 dims x 64 keys (rotated rows)
  __shared__ __bf16 Ps[4][16][72];

  const __bf16* kbase = Kp + (size_t)bh * (SEQ * HD);
  const __bf16* vbase = Vp + (size_t)bh * (SEQ * HD);
  const float* vimpH = vimp + h * SEQ;

  const int rot0 = ((quad + (l16 & 7)) & 7) * 8;        // logical cols quad*8..+7
  const int rot1 = ((quad + 4 + (l16 & 7)) & 7) * 8;    // logical cols 32+quad*8..+7
  const int frow = l16 * 64;

  #pragma unroll 1
  for (int grp = 0; grp < 2; grp++) {
    const int g = grp ? (15 - gg) : gg;
    const int nch = g + 1;
    const int qrow = g * 64 + wave * 16 + l16;
    const __bf16* qp = Qb + (size_t)(b * SEQ + qrow) * D_MODEL + h * HD;
    bf16x8 qa0 = *(const bf16x8*)(qp + quad * 8);        // Q pre-scaled by QSC in gemm
    bf16x8 qa1 = *(const bf16x8*)(qp + 32 + quad * 8);
    float l_i = 0.f;
    f32x4 o[4];
    #pragma unroll
    for (int td = 0; td < 4; td++) { o[td][0] = 0.f; o[td][1] = 0.f; o[td][2] = 0.f; o[td][3] = 0.f; }

    __syncthreads();                      // bufs free of previous group's readers
    async16(&Kl[0][tid * 8], kbase + tid * 8);
    async16(&Kl[0][2048 + tid * 8], kbase + 2048 + tid * 8);
    async16(&Vl[0][tid * 8], vbase + tid * 8);
    async16(&Vl[0][2048 + tid * 8], vbase + 2048 + tid * 8);

    for (int ch = 0; ch < nch; ch++) {
      const int buf = ch & 1;
      __syncthreads();                    // drains DMA for buf (issued ~1 chunk ago)
      if (ch + 1 < nch) {                 // prefetch next chunk into other buffer
        const __bf16* gk = kbase + (ch + 1) * 4096;
        const __bf16* gv = vbase + (ch + 1) * 4096;
        const int nb = buf ^ 1;
        async16(&Kl[nb][tid * 8], gk + tid * 8);
        async16(&Kl[nb][2048 + tid * 8], gk + 2048 + tid * 8);
        async16(&Vl[nb][tid * 8], gv + tid * 8);
        async16(&Vl[nb][2048 + tid * 8], gv + 2048 + tid * 8);
      }
      const int kc = ch * 64;
      float4 vi[4];
      #pragma unroll
      for (int t = 0; t < 4; t++) vi[t] = *(const float4*)(vimpH + kc + t * 16 + quad * 4);
      bf16x8 kf0[4], kf1[4];
      #pragma unroll
      for (int t = 0; t < 4; t++) {
        kf0[t] = *(const bf16x8*)&Kl[buf][t * 1024 + frow + rot0];
        kf1[t] = *(const bf16x8*)&Kl[buf][t * 1024 + frow + rot1];
      }
      bf16x8 vfr0[4], vfr1[4];
      #pragma unroll
      for (int td = 0; td < 4; td++) {
        vfr0[td] = *(const bf16x8*)&Vl[buf][td * 1024 + frow + rot0];
        vfr1[td] = *(const bf16x8*)&Vl[buf][td * 1024 + frow + rot1];
      }
      const f32x4 fz = {0.f, 0.f, 0.f, 0.f};
      float p[4][4];
      float lsum = 0.f;
      #pragma unroll
      for (int t = 0; t < 4; t++) {
        f32x4 sacc = fz;
        sacc = mfma16(kf0[t], qa0, sacc);
        sacc = mfma16(kf1[t], qa1, sacc);
        const float vib[4] = {vi[t].x, vi[t].y, vi[t].z, vi[t].w};
        #pragma unroll
        for (int r = 0; r < 4; r++) {
          float pp = exp2f(sacc[r] + BSC * vib[r]);
          pp = (kc + t * 16 + quad * 4 + r <= qrow) ? pp : 0.f;   // causal (full chunks pass)
          p[t][r] = pp;
          lsum += pp;
        }
      }
      l_i += lsum;
      #pragma unroll
      for (int t = 0; t < 4; t++) {
        union { __bf16 hh[4]; uint2 uu; } pk;
        #pragma unroll
        for (int r = 0; r < 4; r++) pk.hh[r] = (__bf16)p[t][r];
        *(uint2*)&Ps[wave][l16][t * 16 + quad * 4] = pk.uu;
      }
      bf16x8 pf0 = *(const bf16x8*)&Ps[wave][l16][quad * 8];
      bf16x8 pf1 = *(const bf16x8*)&Ps[wave][l16][32 + quad * 8];
      #pragma unroll
      for (int td = 0; td < 4; td++) {
        o[td] = mfma16(vfr0[td], pf0, o[td]);
        o[td] = mfma16(vfr1[td], pf1, o[td]);
      }
    }

    float L = l_i;
    L += __shfl_xor(L, 16);
    L += __shfl_xor(L, 32);
    const float il = 1.0f / L;
    __bf16* op = Ob + (size_t)(b * SEQ + qrow) * D_MODEL + h * HD;
    #pragma unroll
    for (int td = 0; td < 4; td++) {
      union { __bf16 hh[4]; uint2 uu; } pk;
      #pragma unroll
      for (int r = 0; r < 4; r++) pk.hh[r] = (__bf16)(o[td][r] * il);
      *(uint2*)(op + td * 16 + quad * 4) = pk.uu;
    }
  }
}

// ---------------------------------------------------------------------------
extern "C" void kernel_launch(void* const* d_in, const int* in_sizes, int n_in,
                              void* d_out, int out_size, void* d_ws, size_t ws_size,
                              hipStream_t stream) {
  const float* x     = (const float*)d_in[0];
  const float* Wq    = (const float*)d_in[1];
  const float* bq    = (const float*)d_in[2];
  const float* Wk    = (const float*)d_in[3];
  const float* bk    = (const float*)d_in[4];
  const float* Wv    = (const float*)d_in[5];
  const float* bv    = (const float*)d_in[6];
  const float* Wo    = (const float*)d_in[7];
  const float* bo    = (const float*)d_in[8];
  const float* Wimp  = (const float*)d_in[9];
  const float* bimp  = (const float*)d_in[10];
  // d_in[11] = k_ema (unused: kimp bias is per-q-row constant, cancels in softmax)
  const float* v_ema = (const float*)d_in[12];
  float* out = (float*)d_out;

  char* ws = (char*)d_ws;
  __bf16* x_bf  = (__bf16*)(ws);                        // 8 MB
  __bf16* wq_bf = (__bf16*)(ws + (8ull  << 20));        // 2 MB each
  __bf16* wk_bf = (__bf16*)(ws + (10ull << 20));
  __bf16* wv_bf = (__bf16*)(ws + (12ull << 20));
  __bf16* wo_bf = (__bf16*)(ws + (14ull << 20));
  __bf16* q_bf  = (__bf16*)(ws + (16ull << 20));        // 8 MB each
  __bf16* kp_bf = (__bf16*)(ws + (24ull << 20));        // K packed+rotated [bh][key][64]
  __bf16* vp_bf = (__bf16*)(ws + (32ull << 20));        // V packed+rotated [bh][ch][d][64]
  __bf16* a_bf  = (__bf16*)(ws + (40ull << 20));
  float*  vimp  = (float*)(ws + (48ull << 20));         // 64 KB

  prep_kernel<<<12288, 256, 0, stream>>>(
      x, Wq, Wk, Wv, Wo, v_ema, Wimp, bimp,
      x_bf, wq_bf, wk_bf, wv_bf, wo_bf, vimp);

  // Q,K,V projections; Q pre-scaled by 0.125*log2(e); K,V written per-head packed+rotated
  gemm_bt<true><<<dim3(8, 32, 3), 256, 0, stream>>>(
      x_bf, wq_bf, wk_bf, wv_bf, bq, bk, bv,
      (void*)q_bf, (void*)kp_bf, (void*)vp_bf, QSC, 1.0f, 1.0f);

  attn_kernel<<<dim3(512), 256, 0, stream>>>(
      q_bf, kp_bf, vp_bf, vimp, a_bf);

  gemm_bt<false><<<dim3(8, 32, 1), 256, 0, stream>>>(
      a_bf, wo_bf, wo_bf, wo_bf, bo, bo, bo,
      (void*)out, (void*)out, (void*)out, 1.0f, 1.0f, 1.0f);
}